// Round 8
// baseline (4147.897 us; speedup 1.0000x reference)
//
#include <hip/hip_runtime.h>
#include <math.h>

#define NSTEP 64
#define PI_F 3.14159265358979323846f

typedef _Float16 half8 __attribute__((ext_vector_type(8)));
typedef _Float16 half4 __attribute__((ext_vector_type(4)));
typedef float f32x4 __attribute__((ext_vector_type(4)));

#define MFMA(a, b, c) __builtin_amdgcn_mfma_f32_16x16x32_f16(a, b, c, 0, 0, 0)

#define OFF_CAT 49152   // halfs: wcat starts after whh0 (3*128*128)

__device__ __forceinline__ float rcp_fast(float x) { return __builtin_amdgcn_rcpf(x); }
__device__ __forceinline__ float sigmoid_f(float x) {
    float e = __expf(-x);
    return rcp_fast(1.0f + e);
}
__device__ __forceinline__ float tanh_f(float x) {
    float ax = fabsf(x);
    float e  = __expf(-2.0f * ax);
    float t  = (1.0f - e) * rcp_fast(1.0f + e);
    return x >= 0.0f ? t : -t;
}

// Prep: f16 weights; concat [w_ih1|w_hh1] along K for layer 1.
__global__ void prep_kernel(const float* __restrict__ whh0,
                            const float* __restrict__ wih1,
                            const float* __restrict__ whh1,
                            _Float16* __restrict__ wsp) {
    int i = blockIdx.x * 256 + threadIdx.x;
    if (i < 49152) wsp[i] = (_Float16)whh0[i];
    if (i < 98304) {
        int n = i >> 8, k = i & 255;
        float v = (k < 128) ? wih1[(n << 7) + k] : whh1[(n << 7) + k - 128];
        wsp[OFF_CAT + i] = (_Float16)v;
    }
}

// h planes in MFMA-B-frag chunk order:
//   plane[(kc*8 + n)*512 + (q*16 + l4)*8 + j]  = h[e = n*16+l4][dim = 32kc + 8q + j]
// -> a wave's b128 frag read is 64 contiguous 16B chunks: conflict-free.

__global__ __attribute__((amdgpu_flat_work_group_size(512, 512),
                          amdgpu_waves_per_eu(2, 2)))
void rnn_wf_pers(
    const int*   __restrict__ x,
    const float* __restrict__ w_ih0,
    const float* __restrict__ w_lin,
    const float* __restrict__ b_lin,
    const _Float16* __restrict__ wsp,
    float*       __restrict__ out,
    int nbatch)
{
    __shared__ _Float16 h0hi[16384], h0lo[16384];
    __shared__ _Float16 h1hi[16384], h1lo[16384];
    __shared__ float gi0T[2][3][128];          // [prev-bit][gate][dim]
    __shared__ float lsc[2][128][8];           // logit partials [logit][e][wave]
    __shared__ unsigned long long bmk[128];    // per-element bit mask

    const int t    = threadIdx.x;
    const int wv   = t >> 6;        // wave 0..7 -> owns dims [16wv, 16wv+16) per gate
    const int lane = t & 63;
    const int l4   = lane & 15;
    const int q    = lane >> 4;
    const int eb   = blockIdx.x * 128;

    // ---- init LDS ----
    for (int i = t; i < 8192; i += 512) {
        ((int*)h0hi)[i] = 0; ((int*)h0lo)[i] = 0;
        ((int*)h1hi)[i] = 0; ((int*)h1lo)[i] = 0;
    }
    for (int i = t; i < 768; i += 512) {
        int b = i / 384, rem = i - b * 384;
        ((float*)gi0T)[b * 384 + rem] = w_ih0[rem * 2 + b];   // gi0T[b][g][d]
    }
    {   // bit masks: thread t -> element t>>2, quarter t&3
        int el = t >> 2, qq = t & 3;
        int eg = eb + el; if (eg >= nbatch) eg = nbatch - 1;
        const int* xr = x + (size_t)eg * 64 + qq * 16;
        unsigned long long m = 0ull;
#pragma unroll
        for (int i = 0; i < 16; ++i)
            m |= ((unsigned long long)((unsigned)(xr[i] + 1) >> 1)) << (qq * 16 + i);
        m |= __shfl_xor(m, 1);
        m |= __shfl_xor(m, 2);
        if (qq == 0) bmk[el] = m;
    }

    // ---- persistent weight fragments in registers ----
    half8 wl0[3][4], wl1[3][8];
    {
        const _Float16* p0 = wsp;
#pragma unroll
        for (int g = 0; g < 3; ++g)
#pragma unroll
            for (int kc = 0; kc < 4; ++kc)
                wl0[g][kc] = *(const half8*)(p0 + (size_t)(g * 128 + 16 * wv + l4) * 128 + 32 * kc + 8 * q);
        const _Float16* p1 = wsp + OFF_CAT;
#pragma unroll
        for (int g = 0; g < 3; ++g)
#pragma unroll
            for (int kc = 0; kc < 8; ++kc)
                wl1[g][kc] = *(const half8*)(p1 + (size_t)(g * 128 + 16 * wv + l4) * 256 + 32 * kc + 8 * q);
    }
    const int d0 = 16 * wv + 4 * q;            // first of 4 dims this lane updates
    const f32x4 wlin0 = *(const f32x4*)(w_lin + d0);
    const f32x4 wlin1 = *(const f32x4*)(w_lin + 128 + d0);
    const float bl0 = b_lin[0], bl1 = b_lin[1];

    // addressing helpers
    const int lo8 = ((q << 4) + l4) << 3;           // lane chunk offset (halfs)
    const int kcw = d0 >> 5;                        // epilogue chunk coords
    const int r8  = (d0 >> 3) & 3;
    const int eoff = d0 & 7;
    const int ep0 = kcw * 4096 + r8 * 128 + l4 * 8 + eoff;  // + n*512

    const int eh = 16 * wv + l4;                    // head element (replicated over q)
    float amp = 1.0f, phs = 0.0f, nu = 0.0f, nd = 0.0f;

    half4 sh[8], sl[8];

    __syncthreads();

    for (int step = 0; step < NSTEP; ++step) {
        // ================= Layer 0 =================
#pragma unroll
        for (int n = 0; n < 8; ++n) {
            f32x4 aR = {0, 0, 0, 0}, aZ = {0, 0, 0, 0}, aN = {0, 0, 0, 0};
#pragma unroll
            for (int kc = 0; kc < 4; ++kc) {
                const int cb = (kc * 8 + n) * 512 + lo8;
                half8 hh = *(const half8*)&h0hi[cb];
                half8 hl = *(const half8*)&h0lo[cb];
                aR = MFMA(wl0[0][kc], hh, aR);
                aZ = MFMA(wl0[1][kc], hh, aZ);
                aN = MFMA(wl0[2][kc], hh, aN);
                aR = MFMA(wl0[0][kc], hl, aR);
                aZ = MFMA(wl0[1][kc], hl, aZ);
                aN = MFMA(wl0[2][kc], hl, aN);
            }
            const int e = n * 16 + l4;
            f32x4 giR = {0, 0, 0, 0}, giZ = {0, 0, 0, 0}, giN = {0, 0, 0, 0};
            if (step > 0) {
                int pb = (int)((bmk[e] >> (step - 1)) & 1ull);
                const float* gp = &gi0T[pb][0][0];
                giR = *(const f32x4*)(gp + d0);
                giZ = *(const f32x4*)(gp + 128 + d0);
                giN = *(const f32x4*)(gp + 256 + d0);
            }
            half4 hph = *(const half4*)&h0hi[ep0 + n * 512];
            half4 hpl = *(const half4*)&h0lo[ep0 + n * 512];
            half4 nh, nl;
#pragma unroll
            for (int r = 0; r < 4; ++r) {
                float rr = sigmoid_f(giR[r] + aR[r]);
                float zz = sigmoid_f(giZ[r] + aZ[r]);
                float nn = tanh_f(giN[r] + rr * aN[r]);
                float hprev = (float)hph[r] + (float)hpl[r];
                float hn = (1.0f - zz) * nn + zz * hprev;
                _Float16 hi = (_Float16)hn;
                nh[r] = hi;
                nl[r] = (_Float16)(hn - (float)hi);
            }
            sh[n] = nh; sl[n] = nl;
        }
        __syncthreads();   // B1: all layer-0 reads of h0 done
#pragma unroll
        for (int n = 0; n < 8; ++n) {
            *(half4*)&h0hi[ep0 + n * 512] = sh[n];
            *(half4*)&h0lo[ep0 + n * 512] = sl[n];
        }
        __syncthreads();   // B2: h0 new visible

        // ===== Layer 1: K = [h0 (kc<4) ; h1 (kc>=4)], N-gate split =====
#pragma unroll
        for (int n = 0; n < 8; ++n) {
            f32x4 aR = {0, 0, 0, 0}, aZ = {0, 0, 0, 0};
            f32x4 aNi = {0, 0, 0, 0}, aNh = {0, 0, 0, 0};
#pragma unroll
            for (int kc = 0; kc < 8; ++kc) {
                const int cb = ((kc & 3) * 8 + n) * 512 + lo8;
                half8 hh, hl;
                if (kc < 4) {
                    hh = *(const half8*)&h0hi[cb];
                    hl = *(const half8*)&h0lo[cb];
                } else {
                    hh = *(const half8*)&h1hi[cb];
                    hl = *(const half8*)&h1lo[cb];
                }
                aR = MFMA(wl1[0][kc], hh, aR);
                aZ = MFMA(wl1[1][kc], hh, aZ);
                aR = MFMA(wl1[0][kc], hl, aR);
                aZ = MFMA(wl1[1][kc], hl, aZ);
                if (kc < 4) {
                    aNi = MFMA(wl1[2][kc], hh, aNi);
                    aNi = MFMA(wl1[2][kc], hl, aNi);
                } else {
                    aNh = MFMA(wl1[2][kc], hh, aNh);
                    aNh = MFMA(wl1[2][kc], hl, aNh);
                }
            }
            const int e = n * 16 + l4;
            half4 hph = *(const half4*)&h1hi[ep0 + n * 512];
            half4 hpl = *(const half4*)&h1lo[ep0 + n * 512];
            float l0p = 0.0f, l1p = 0.0f;
            half4 nh, nl;
#pragma unroll
            for (int r = 0; r < 4; ++r) {
                float rr = sigmoid_f(aR[r]);
                float zz = sigmoid_f(aZ[r]);
                float nn = tanh_f(aNi[r] + rr * aNh[r]);
                float hprev = (float)hph[r] + (float)hpl[r];
                float hn = (1.0f - zz) * nn + zz * hprev;
                l0p = fmaf(hn, wlin0[r], l0p);
                l1p = fmaf(hn, wlin1[r], l1p);
                _Float16 hi = (_Float16)hn;
                nh[r] = hi;
                nl[r] = (_Float16)(hn - (float)hi);
            }
            sh[n] = nh; sl[n] = nl;
            l0p += __shfl_xor(l0p, 16); l0p += __shfl_xor(l0p, 32);
            l1p += __shfl_xor(l1p, 16); l1p += __shfl_xor(l1p, 32);
            if (q == 0) { lsc[0][e][wv] = l0p; lsc[1][e][wv] = l1p; }
        }
        __syncthreads();   // B3: layer-1 reads + lsc writes done
#pragma unroll
        for (int n = 0; n < 8; ++n) {
            *(half4*)&h1hi[ep0 + n * 512] = sh[n];
            *(half4*)&h1lo[ep0 + n * 512] = sl[n];
        }

        // ================= head (element eh, replicated across q) =================
        {
            f32x4 a0 = *(const f32x4*)&lsc[0][eh][0];
            f32x4 a1 = *(const f32x4*)&lsc[0][eh][4];
            f32x4 b0 = *(const f32x4*)&lsc[1][eh][0];
            f32x4 b1 = *(const f32x4*)&lsc[1][eh][4];
            float l0 = a0[0] + a0[1] + a0[2] + a0[3] + a1[0] + a1[1] + a1[2] + a1[3] + bl0;
            float l1 = b0[0] + b0[1] + b0[2] + b0[3] + b1[0] + b1[1] + b1[2] + b1[3] + bl1;

            float p0 = sigmoid_f(l0 - l1);
            float p1 = sigmoid_f(l1 - l0);
            float y0 = sqrtf(p0), y1 = sqrtf(p1);
            float ph0 = PI_F * l0 * rcp_fast(1.0f + fabsf(l0));
            float ph1 = PI_F * l1 * rcp_fast(1.0f + fabsf(l1));

            int bit = (int)((bmk[eh] >> step) & 1ull);
            bool is_even = (step & 1) == 0;
            float num   = is_even ? nu : nd;
            float lower = -16.0f + (float)(step >> 1);
            float occ   = (num < 16.0f) ? 1.0f : 0.0f;
            float unocc = (num > lower) ? 1.0f : 0.0f;
            if (step >= 16) {
                float m0 = y0 * unocc, m1 = y1 * occ;
                float nrm = fmaxf(sqrtf(m0 * m0 + m1 * m1), 1e-12f);
                float rn  = rcp_fast(nrm);
                y0 = m0 * rn; y1 = m1 * rn;
            }
            if (is_even) nu += (float)bit; else nd += (float)bit;
            amp *= bit ? y1 : y0;
            phs += bit ? ph1 : ph0;
        }
        // no barrier here: next step's B1/B2 fence h1/lsc before reuse
    }

    if (q == 0) {
        int eg = eb + eh;
        if (eg < nbatch) {
            float s, c;
            sincosf(phs, &s, &c);
            out[eg]          = amp * c;
            out[nbatch + eg] = amp * s;
        }
    }
}

extern "C" void kernel_launch(void* const* d_in, const int* in_sizes, int n_in,
                              void* d_out, int out_size, void* d_ws, size_t ws_size,
                              hipStream_t stream) {
    const int*   x     = (const int*)  d_in[0];
    const float* w_ih0 = (const float*)d_in[1];
    const float* w_hh0 = (const float*)d_in[2];
    const float* w_ih1 = (const float*)d_in[3];
    const float* w_hh1 = (const float*)d_in[4];
    const float* w_lin = (const float*)d_in[5];
    const float* b_lin = (const float*)d_in[6];
    float* out = (float*)d_out;
    _Float16* wsp = (_Float16*)d_ws;

    const int nbatch = in_sizes[0] / 64;

    prep_kernel<<<384, 256, 0, stream>>>(w_hh0, w_ih1, w_hh1, wsp);

    const int blocks = (nbatch + 127) / 128;
    rnn_wf_pers<<<blocks, 512, 0, stream>>>(x, w_ih0, w_lin, b_lin, wsp, out, nbatch);
}

// Round 10
// 4141.381 us; speedup vs baseline: 1.0016x; 1.0016x over previous
//
#include <hip/hip_runtime.h>
#include <math.h>

#define NSTEP 64
#define PI_F 3.14159265358979323846f

typedef _Float16 half8 __attribute__((ext_vector_type(8)));
typedef _Float16 half4 __attribute__((ext_vector_type(4)));
typedef float f32x4 __attribute__((ext_vector_type(4)));

#define MFMA(a, b, c) __builtin_amdgcn_mfma_f32_16x16x32_f16(a, b, c, 0, 0, 0)

#define OFF_CAT 49152   // halfs: wcat starts after whh0 (3*128*128)

__device__ __forceinline__ float rcp_fast(float x) { return __builtin_amdgcn_rcpf(x); }
__device__ __forceinline__ float sigmoid_f(float x) {
    float e = __expf(-x);
    return rcp_fast(1.0f + e);
}
__device__ __forceinline__ float tanh_f(float x) {
    float ax = fabsf(x);
    float e  = __expf(-2.0f * ax);
    float t  = (1.0f - e) * rcp_fast(1.0f + e);
    return x >= 0.0f ? t : -t;
}

// Prep: f16 weights; concat [w_ih1|w_hh1] along K for layer 1.
__global__ void prep_kernel(const float* __restrict__ whh0,
                            const float* __restrict__ wih1,
                            const float* __restrict__ whh1,
                            _Float16* __restrict__ wsp) {
    int i = blockIdx.x * 256 + threadIdx.x;
    if (i < 49152) wsp[i] = (_Float16)whh0[i];
    if (i < 98304) {
        int n = i >> 8, k = i & 255;
        float v = (k < 128) ? wih1[(n << 7) + k] : whh1[(n << 7) + k - 128];
        wsp[OFF_CAT + i] = (_Float16)v;
    }
}

// h planes in MFMA-B-frag chunk order:
//   plane[(kc*8 + n)*512 + (q*16 + l4)*8 + j]  = h[e = n*16+l4][dim = 32kc + 8q + j]
// -> a wave's b128 frag read is 64 contiguous 16B chunks: conflict-free.

__global__ void __launch_bounds__(512, 1) rnn_wf_pers(
    const int*   __restrict__ x,
    const float* __restrict__ w_ih0,
    const float* __restrict__ w_lin,
    const float* __restrict__ b_lin,
    const _Float16* __restrict__ wsp,
    float*       __restrict__ out,
    int nbatch)
{
    __shared__ _Float16 h0hi[16384], h0lo[16384];
    __shared__ _Float16 h1hi[16384], h1lo[16384];
    __shared__ float gi0T[2][3][128];          // [prev-bit][gate][dim]
    __shared__ float lsc[2][128][8];           // logit partials [logit][e][wave]
    __shared__ unsigned long long bmk[128];    // per-element bit mask

    const int t    = threadIdx.x;
    const int wv   = t >> 6;        // wave 0..7 -> owns dims [16wv, 16wv+16) per gate
    const int lane = t & 63;
    const int l4   = lane & 15;
    const int q    = lane >> 4;
    const int eb   = blockIdx.x * 128;

    // ---- init LDS ----
    for (int i = t; i < 8192; i += 512) {
        ((int*)h0hi)[i] = 0; ((int*)h0lo)[i] = 0;
        ((int*)h1hi)[i] = 0; ((int*)h1lo)[i] = 0;
    }
    for (int i = t; i < 768; i += 512) {
        int b = i / 384, rem = i - b * 384;
        ((float*)gi0T)[b * 384 + rem] = w_ih0[rem * 2 + b];   // gi0T[b][g][d]
    }
    {   // bit masks: thread t -> element t>>2, quarter t&3
        int el = t >> 2, qq = t & 3;
        int eg = eb + el; if (eg >= nbatch) eg = nbatch - 1;
        const int* xr = x + (size_t)eg * 64 + qq * 16;
        unsigned long long m = 0ull;
#pragma unroll
        for (int i = 0; i < 16; ++i)
            m |= ((unsigned long long)((unsigned)(xr[i] + 1) >> 1)) << (qq * 16 + i);
        m |= __shfl_xor(m, 1);
        m |= __shfl_xor(m, 2);
        if (qq == 0) bmk[el] = m;
    }

    // ---- persistent weight fragments in registers ----
    half8 wl0[3][4], wl1[3][8];
    {
        const _Float16* p0 = wsp;
#pragma unroll
        for (int g = 0; g < 3; ++g)
#pragma unroll
            for (int kc = 0; kc < 4; ++kc)
                wl0[g][kc] = *(const half8*)(p0 + (size_t)(g * 128 + 16 * wv + l4) * 128 + 32 * kc + 8 * q);
        const _Float16* p1 = wsp + OFF_CAT;
#pragma unroll
        for (int g = 0; g < 3; ++g)
#pragma unroll
            for (int kc = 0; kc < 8; ++kc)
                wl1[g][kc] = *(const half8*)(p1 + (size_t)(g * 128 + 16 * wv + l4) * 256 + 32 * kc + 8 * q);
    }
    const int d0 = 16 * wv + 4 * q;            // first of 4 dims this lane updates
    const f32x4 wlin0 = *(const f32x4*)(w_lin + d0);
    const f32x4 wlin1 = *(const f32x4*)(w_lin + 128 + d0);
    const float bl0 = b_lin[0], bl1 = b_lin[1];

    // addressing helpers
    const int lo8 = ((q << 4) + l4) << 3;           // lane chunk offset (halfs)
    const int kcw = d0 >> 5;                        // epilogue chunk coords
    const int r8  = (d0 >> 3) & 3;
    const int eoff = d0 & 7;
    const int ep0 = kcw * 4096 + r8 * 128 + l4 * 8 + eoff;  // + n*512

    const int eh = 16 * wv + l4;                    // head element (replicated over q)
    float amp = 1.0f, phs = 0.0f, nu = 0.0f, nd = 0.0f;

    half4 sh[8], sl[8];

    __syncthreads();

    for (int step = 0; step < NSTEP; ++step) {
        // ================= Layer 0 =================
#pragma unroll
        for (int n = 0; n < 8; ++n) {
            f32x4 aR = {0, 0, 0, 0}, aZ = {0, 0, 0, 0}, aN = {0, 0, 0, 0};
#pragma unroll
            for (int kc = 0; kc < 4; ++kc) {
                const int cb = (kc * 8 + n) * 512 + lo8;
                half8 hh = *(const half8*)&h0hi[cb];
                half8 hl = *(const half8*)&h0lo[cb];
                aR = MFMA(wl0[0][kc], hh, aR);
                aZ = MFMA(wl0[1][kc], hh, aZ);
                aN = MFMA(wl0[2][kc], hh, aN);
                aR = MFMA(wl0[0][kc], hl, aR);
                aZ = MFMA(wl0[1][kc], hl, aZ);
                aN = MFMA(wl0[2][kc], hl, aN);
            }
            const int e = n * 16 + l4;
            f32x4 giR = {0, 0, 0, 0}, giZ = {0, 0, 0, 0}, giN = {0, 0, 0, 0};
            if (step > 0) {
                int pb = (int)((bmk[e] >> (step - 1)) & 1ull);
                const float* gp = &gi0T[pb][0][0];
                giR = *(const f32x4*)(gp + d0);
                giZ = *(const f32x4*)(gp + 128 + d0);
                giN = *(const f32x4*)(gp + 256 + d0);
            }
            half4 hph = *(const half4*)&h0hi[ep0 + n * 512];
            half4 hpl = *(const half4*)&h0lo[ep0 + n * 512];
            half4 nh, nl;
#pragma unroll
            for (int r = 0; r < 4; ++r) {
                float rr = sigmoid_f(giR[r] + aR[r]);
                float zz = sigmoid_f(giZ[r] + aZ[r]);
                float nn = tanh_f(giN[r] + rr * aN[r]);
                float hprev = (float)hph[r] + (float)hpl[r];
                float hn = (1.0f - zz) * nn + zz * hprev;
                _Float16 hi = (_Float16)hn;
                nh[r] = hi;
                nl[r] = (_Float16)(hn - (float)hi);
            }
            sh[n] = nh; sl[n] = nl;
        }
        __syncthreads();   // B1: all layer-0 reads of h0 done
#pragma unroll
        for (int n = 0; n < 8; ++n) {
            *(half4*)&h0hi[ep0 + n * 512] = sh[n];
            *(half4*)&h0lo[ep0 + n * 512] = sl[n];
        }
        __syncthreads();   // B2: h0 new visible

        // ===== Layer 1: K = [h0 (kc<4) ; h1 (kc>=4)], N-gate split =====
#pragma unroll
        for (int n = 0; n < 8; ++n) {
            f32x4 aR = {0, 0, 0, 0}, aZ = {0, 0, 0, 0};
            f32x4 aNi = {0, 0, 0, 0}, aNh = {0, 0, 0, 0};
#pragma unroll
            for (int kc = 0; kc < 8; ++kc) {
                const int cb = ((kc & 3) * 8 + n) * 512 + lo8;
                half8 hh, hl;
                if (kc < 4) {
                    hh = *(const half8*)&h0hi[cb];
                    hl = *(const half8*)&h0lo[cb];
                } else {
                    hh = *(const half8*)&h1hi[cb];
                    hl = *(const half8*)&h1lo[cb];
                }
                aR = MFMA(wl1[0][kc], hh, aR);
                aZ = MFMA(wl1[1][kc], hh, aZ);
                aR = MFMA(wl1[0][kc], hl, aR);
                aZ = MFMA(wl1[1][kc], hl, aZ);
                if (kc < 4) {
                    aNi = MFMA(wl1[2][kc], hh, aNi);
                    aNi = MFMA(wl1[2][kc], hl, aNi);
                } else {
                    aNh = MFMA(wl1[2][kc], hh, aNh);
                    aNh = MFMA(wl1[2][kc], hl, aNh);
                }
            }
            const int e = n * 16 + l4;
            half4 hph = *(const half4*)&h1hi[ep0 + n * 512];
            half4 hpl = *(const half4*)&h1lo[ep0 + n * 512];
            float l0p = 0.0f, l1p = 0.0f;
            half4 nh, nl;
#pragma unroll
            for (int r = 0; r < 4; ++r) {
                float rr = sigmoid_f(aR[r]);
                float zz = sigmoid_f(aZ[r]);
                float nn = tanh_f(aNi[r] + rr * aNh[r]);
                float hprev = (float)hph[r] + (float)hpl[r];
                float hn = (1.0f - zz) * nn + zz * hprev;
                l0p = fmaf(hn, wlin0[r], l0p);
                l1p = fmaf(hn, wlin1[r], l1p);
                _Float16 hi = (_Float16)hn;
                nh[r] = hi;
                nl[r] = (_Float16)(hn - (float)hi);
            }
            sh[n] = nh; sl[n] = nl;
            l0p += __shfl_xor(l0p, 16); l0p += __shfl_xor(l0p, 32);
            l1p += __shfl_xor(l1p, 16); l1p += __shfl_xor(l1p, 32);
            if (q == 0) { lsc[0][e][wv] = l0p; lsc[1][e][wv] = l1p; }
        }
        __syncthreads();   // B3: layer-1 reads + lsc writes done
#pragma unroll
        for (int n = 0; n < 8; ++n) {
            *(half4*)&h1hi[ep0 + n * 512] = sh[n];
            *(half4*)&h1lo[ep0 + n * 512] = sl[n];
        }

        // ================= head (element eh, replicated across q) =================
        {
            f32x4 a0 = *(const f32x4*)&lsc[0][eh][0];
            f32x4 a1 = *(const f32x4*)&lsc[0][eh][4];
            f32x4 b0 = *(const f32x4*)&lsc[1][eh][0];
            f32x4 b1 = *(const f32x4*)&lsc[1][eh][4];
            float l0 = a0[0] + a0[1] + a0[2] + a0[3] + a1[0] + a1[1] + a1[2] + a1[3] + bl0;
            float l1 = b0[0] + b0[1] + b0[2] + b0[3] + b1[0] + b1[1] + b1[2] + b1[3] + bl1;

            float p0 = sigmoid_f(l0 - l1);
            float p1 = sigmoid_f(l1 - l0);
            float y0 = sqrtf(p0), y1 = sqrtf(p1);
            float ph0 = PI_F * l0 * rcp_fast(1.0f + fabsf(l0));
            float ph1 = PI_F * l1 * rcp_fast(1.0f + fabsf(l1));

            int bit = (int)((bmk[eh] >> step) & 1ull);
            bool is_even = (step & 1) == 0;
            float num   = is_even ? nu : nd;
            float lower = -16.0f + (float)(step >> 1);
            float occ   = (num < 16.0f) ? 1.0f : 0.0f;
            float unocc = (num > lower) ? 1.0f : 0.0f;
            if (step >= 16) {
                float m0 = y0 * unocc, m1 = y1 * occ;
                float nrm = fmaxf(sqrtf(m0 * m0 + m1 * m1), 1e-12f);
                float rn  = rcp_fast(nrm);
                y0 = m0 * rn; y1 = m1 * rn;
            }
            if (is_even) nu += (float)bit; else nd += (float)bit;
            amp *= bit ? y1 : y0;
            phs += bit ? ph1 : ph0;
        }
        // no barrier here: next step's B1/B2 fence h1/lsc before reuse
    }

    if (q == 0) {
        int eg = eb + eh;
        if (eg < nbatch) {
            float s, c;
            sincosf(phs, &s, &c);
            out[eg]          = amp * c;
            out[nbatch + eg] = amp * s;
        }
    }
}

extern "C" void kernel_launch(void* const* d_in, const int* in_sizes, int n_in,
                              void* d_out, int out_size, void* d_ws, size_t ws_size,
                              hipStream_t stream) {
    const int*   x     = (const int*)  d_in[0];
    const float* w_ih0 = (const float*)d_in[1];
    const float* w_hh0 = (const float*)d_in[2];
    const float* w_ih1 = (const float*)d_in[3];
    const float* w_hh1 = (const float*)d_in[4];
    const float* w_lin = (const float*)d_in[5];
    const float* b_lin = (const float*)d_in[6];
    float* out = (float*)d_out;
    _Float16* wsp = (_Float16*)d_ws;

    const int nbatch = in_sizes[0] / 64;

    prep_kernel<<<384, 256, 0, stream>>>(w_hh0, w_ih1, w_hh1, wsp);

    const int blocks = (nbatch + 127) / 128;
    rnn_wf_pers<<<blocks, 512, 0, stream>>>(x, w_ih0, w_lin, b_lin, wsp, out, nbatch);
}

// Round 11
// 3240.523 us; speedup vs baseline: 1.2800x; 1.2780x over previous
//
#include <hip/hip_runtime.h>
#include <math.h>

#define NSTEP 64
#define PI_F 3.14159265358979323846f

typedef _Float16 half8 __attribute__((ext_vector_type(8)));
typedef _Float16 half4 __attribute__((ext_vector_type(4)));
typedef float f32x4 __attribute__((ext_vector_type(4)));

#define MFMA(a, b, c) __builtin_amdgcn_mfma_f32_16x16x32_f16(a, b, c, 0, 0, 0)
#define OFF_CAT 49152   // halfs: wcat starts after whh0 (3*128*128)

__device__ __forceinline__ float rcp_fast(float x) { return __builtin_amdgcn_rcpf(x); }
__device__ __forceinline__ float sigmoid_f(float x) {
    float e = __expf(-x);
    return rcp_fast(1.0f + e);
}
__device__ __forceinline__ float tanh_f(float x) {
    float ax = fabsf(x);
    float e  = __expf(-2.0f * ax);
    float t  = (1.0f - e) * rcp_fast(1.0f + e);
    return x >= 0.0f ? t : -t;
}

// Prep: f16 weights; concat [w_ih1|w_hh1] along K for layer 1.
__global__ void prep_kernel(const float* __restrict__ whh0,
                            const float* __restrict__ wih1,
                            const float* __restrict__ whh1,
                            _Float16* __restrict__ wsp) {
    int i = blockIdx.x * 256 + threadIdx.x;
    if (i < 49152) wsp[i] = (_Float16)whh0[i];
    if (i < 98304) {
        int n = i >> 8, k = i & 255;
        float v = (k < 128) ? wih1[(n << 7) + k] : whh1[(n << 7) + k - 128];
        wsp[OFF_CAT + i] = (_Float16)v;
    }
}

// h planes (64 elems) in MFMA-B-frag chunk order, double-buffered by step parity:
//   plane[buf][(kc*4 + n)*512 + (q*16 + l4)*8 + j] = h[e = n*16+l4][dim = 32kc + 8q + j]
// Pipeline (tick p): L0 waves (0-7) compute h0(p): read h0[prv], write h0[cur].
//                    L1 waves (8-15) compute h1(p-1): read h0[prv] + h1[cur], write h1[prv].
//                    Head (waves 0-3) for step p-2: read h1[cur]. One barrier per tick.

__global__ void __launch_bounds__(1024, 1) rnn_wf_pipe(
    const int*   __restrict__ x,
    const float* __restrict__ w_ih0,
    const float* __restrict__ w_lin,
    const float* __restrict__ b_lin,
    const _Float16* __restrict__ wsp,
    float*       __restrict__ out,
    int nbatch)
{
    __shared__ _Float16 h0hi[2][8192], h0lo[2][8192];
    __shared__ _Float16 h1hi[2][8192], h1lo[2][8192];
    __shared__ float gi0T[2][3][128];          // [prev-bit][gate][dim]
    __shared__ float wlinT[256];               // w_lin flat
    __shared__ unsigned long long bmk[64];     // per-element bit mask

    const int t    = threadIdx.x;
    const int wv   = t >> 6;
    const int l4   = t & 15;
    const int q    = (t >> 4) & 3;
    const int wvd  = wv & 7;                   // dim-slot within layer group
    const int eb   = blockIdx.x * 64;

    // ---- init LDS ----
    for (int i = t; i < 8192; i += 1024) {     // 8192 ints = 2 bufs x 8192 halfs per array
        ((int*)h0hi)[i] = 0; ((int*)h0lo)[i] = 0;
        ((int*)h1hi)[i] = 0; ((int*)h1lo)[i] = 0;
    }
    if (t < 768) {
        int b = t / 384, rem = t - b * 384;
        ((float*)gi0T)[b * 384 + rem] = w_ih0[rem * 2 + b];
    }
    if (t < 256) wlinT[t] = w_lin[t];
    if (t < 256) {   // bit masks: thread t -> element t>>2, quarter t&3
        int el = t >> 2, qq = t & 3;
        int eg = eb + el; if (eg >= nbatch) eg = nbatch - 1;
        const int* xr = x + (size_t)eg * 64 + qq * 16;
        unsigned long long m = 0ull;
#pragma unroll
        for (int i = 0; i < 16; ++i)
            m |= ((unsigned long long)((unsigned)(xr[i] + 1) >> 1)) << (qq * 16 + i);
        m |= __shfl_xor(m, 1);
        m |= __shfl_xor(m, 2);
        if (qq == 0) bmk[el] = m;
    }

    const int lo8 = ((q << 4) + l4) << 3;      // B-frag lane chunk offset (halfs)
    const int d0  = 16 * wvd + 4 * q;          // first of 4 dims this lane updates
    const int ep0 = (d0 >> 5) * 2048 + ((d0 >> 3) & 3) * 128 + l4 * 8 + (d0 & 7);

    __syncthreads();

    if (wv < 8) {
        // ================= Layer-0 + head waves =================
        half8 wl0[3][4];
#pragma unroll
        for (int g = 0; g < 3; ++g)
#pragma unroll
            for (int kc = 0; kc < 4; ++kc)
                wl0[g][kc] = *(const half8*)(wsp + (size_t)(g * 128 + 16 * wvd + l4) * 128 + 32 * kc + 8 * q);

        const float bl0 = b_lin[0], bl1 = b_lin[1];
        const int eh = 16 * wv + l4;           // head element (wv<4), q-replicated
        float amp = 1.0f, phs = 0.0f, nu = 0.0f, nd = 0.0f;

        for (int tick = 0; tick < 66; ++tick) {
            const int cur = tick & 1, prv = cur ^ 1;
            if (tick < 64) {
                // h0(tick) = GRU0(onehot(bit(tick-1)), h0(tick-1))
#pragma unroll
                for (int n = 0; n < 4; ++n) {
                    f32x4 aR = {0,0,0,0}, aZ = {0,0,0,0}, aN = {0,0,0,0};
#pragma unroll
                    for (int kc = 0; kc < 4; ++kc) {
                        const int cb = (kc * 4 + n) * 512 + lo8;
                        half8 hh = *(const half8*)&h0hi[prv][cb];
                        half8 hl = *(const half8*)&h0lo[prv][cb];
                        aR = MFMA(wl0[0][kc], hh, aR);
                        aZ = MFMA(wl0[1][kc], hh, aZ);
                        aN = MFMA(wl0[2][kc], hh, aN);
                        aR = MFMA(wl0[0][kc], hl, aR);
                        aZ = MFMA(wl0[1][kc], hl, aZ);
                        aN = MFMA(wl0[2][kc], hl, aN);
                    }
                    const int e = n * 16 + l4;
                    f32x4 giR = {0,0,0,0}, giZ = {0,0,0,0}, giN = {0,0,0,0};
                    if (tick > 0) {
                        int pb = (int)((bmk[e] >> (tick - 1)) & 1ull);
                        const float* gp = &gi0T[pb][0][0];
                        giR = *(const f32x4*)(gp + d0);
                        giZ = *(const f32x4*)(gp + 128 + d0);
                        giN = *(const f32x4*)(gp + 256 + d0);
                    }
                    half4 hph = *(const half4*)&h0hi[prv][ep0 + n * 512];
                    half4 hpl = *(const half4*)&h0lo[prv][ep0 + n * 512];
                    half4 nh, nl;
#pragma unroll
                    for (int r = 0; r < 4; ++r) {
                        float rr = sigmoid_f(giR[r] + aR[r]);
                        float zz = sigmoid_f(giZ[r] + aZ[r]);
                        float nn = tanh_f(giN[r] + rr * aN[r]);
                        float hprev = (float)hph[r] + (float)hpl[r];
                        float hn = (1.0f - zz) * nn + zz * hprev;
                        _Float16 hi = (_Float16)hn;
                        nh[r] = hi;
                        nl[r] = (_Float16)(hn - (float)hi);
                    }
                    *(half4*)&h0hi[cur][ep0 + n * 512] = nh;
                    *(half4*)&h0lo[cur][ep0 + n * 512] = nl;
                }
            }
            if (wv < 4 && tick >= 2) {
                // head for step s = tick-2; h1(s) lives in buf s&1 == tick&1 == cur
                const int s = tick - 2;
                float l0 = 0.0f, l1 = 0.0f;
#pragma unroll
                for (int qq = 0; qq < 4; ++qq) {   // this q-copy handles kc = q
                    const int cb = (q * 4 + wv) * 512 + (qq * 16 + l4) * 8;
                    half8 hh = *(const half8*)&h1hi[cur][cb];
                    half8 hl = *(const half8*)&h1lo[cur][cb];
                    const float* wp = &wlinT[32 * q + 8 * qq];
#pragma unroll
                    for (int j = 0; j < 8; ++j) {
                        float hv = (float)hh[j] + (float)hl[j];
                        l0 = fmaf(hv, wp[j], l0);
                        l1 = fmaf(hv, wp[128 + j], l1);
                    }
                }
                l0 += __shfl_xor(l0, 16); l0 += __shfl_xor(l0, 32); l0 += bl0;
                l1 += __shfl_xor(l1, 16); l1 += __shfl_xor(l1, 32); l1 += bl1;

                float p0 = sigmoid_f(l0 - l1);
                float p1 = sigmoid_f(l1 - l0);
                float y0 = sqrtf(p0), y1 = sqrtf(p1);
                float ph0 = PI_F * l0 * rcp_fast(1.0f + fabsf(l0));
                float ph1 = PI_F * l1 * rcp_fast(1.0f + fabsf(l1));

                int bit = (int)((bmk[eh] >> s) & 1ull);
                bool is_even = (s & 1) == 0;
                float num   = is_even ? nu : nd;
                float lower = -16.0f + (float)(s >> 1);
                float occ   = (num < 16.0f) ? 1.0f : 0.0f;
                float unocc = (num > lower) ? 1.0f : 0.0f;
                if (s >= 16) {
                    float m0 = y0 * unocc, m1 = y1 * occ;
                    float nrm = fmaxf(sqrtf(m0 * m0 + m1 * m1), 1e-12f);
                    float rn  = rcp_fast(nrm);
                    y0 = m0 * rn; y1 = m1 * rn;
                }
                if (is_even) nu += (float)bit; else nd += (float)bit;
                amp *= bit ? y1 : y0;
                phs += bit ? ph1 : ph0;
            }
            __syncthreads();
        }

        if (wv < 4 && q == 0) {
            int eg = eb + eh;
            if (eg < nbatch) {
                float s, c;
                sincosf(phs, &s, &c);
                out[eg]          = amp * c;
                out[nbatch + eg] = amp * s;
            }
        }
    } else {
        // ================= Layer-1 waves =================
        half8 wl1[3][8];
#pragma unroll
        for (int g = 0; g < 3; ++g)
#pragma unroll
            for (int kc = 0; kc < 8; ++kc)
                wl1[g][kc] = *(const half8*)(wsp + OFF_CAT + (size_t)(g * 128 + 16 * wvd + l4) * 256 + 32 * kc + 8 * q);

        for (int tick = 0; tick < 66; ++tick) {
            const int cur = tick & 1, prv = cur ^ 1;
            if (tick >= 1 && tick < 65) {
                // h1(tick-1) = GRU1(h0(tick-1), h1(tick-2)): read h0[prv], h1[cur]; write h1[prv]
#pragma unroll
                for (int n = 0; n < 4; ++n) {
                    f32x4 aR = {0,0,0,0}, aZ = {0,0,0,0};
                    f32x4 aNi = {0,0,0,0}, aNh = {0,0,0,0};
#pragma unroll
                    for (int kc = 0; kc < 8; ++kc) {
                        const int cb = ((kc & 3) * 4 + n) * 512 + lo8;
                        half8 hh, hl;
                        if (kc < 4) {
                            hh = *(const half8*)&h0hi[prv][cb];
                            hl = *(const half8*)&h0lo[prv][cb];
                        } else {
                            hh = *(const half8*)&h1hi[cur][cb];
                            hl = *(const half8*)&h1lo[cur][cb];
                        }
                        aR = MFMA(wl1[0][kc], hh, aR);
                        aZ = MFMA(wl1[1][kc], hh, aZ);
                        aR = MFMA(wl1[0][kc], hl, aR);
                        aZ = MFMA(wl1[1][kc], hl, aZ);
                        if (kc < 4) {
                            aNi = MFMA(wl1[2][kc], hh, aNi);
                            aNi = MFMA(wl1[2][kc], hl, aNi);
                        } else {
                            aNh = MFMA(wl1[2][kc], hh, aNh);
                            aNh = MFMA(wl1[2][kc], hl, aNh);
                        }
                    }
                    half4 hph = *(const half4*)&h1hi[cur][ep0 + n * 512];
                    half4 hpl = *(const half4*)&h1lo[cur][ep0 + n * 512];
                    half4 nh, nl;
#pragma unroll
                    for (int r = 0; r < 4; ++r) {
                        float rr = sigmoid_f(aR[r]);
                        float zz = sigmoid_f(aZ[r]);
                        float nn = tanh_f(aNi[r] + rr * aNh[r]);
                        float hprev = (float)hph[r] + (float)hpl[r];
                        float hn = (1.0f - zz) * nn + zz * hprev;
                        _Float16 hi = (_Float16)hn;
                        nh[r] = hi;
                        nl[r] = (_Float16)(hn - (float)hi);
                    }
                    *(half4*)&h1hi[prv][ep0 + n * 512] = nh;
                    *(half4*)&h1lo[prv][ep0 + n * 512] = nl;
                }
            }
            __syncthreads();
        }
    }
}

extern "C" void kernel_launch(void* const* d_in, const int* in_sizes, int n_in,
                              void* d_out, int out_size, void* d_ws, size_t ws_size,
                              hipStream_t stream) {
    const int*   x     = (const int*)  d_in[0];
    const float* w_ih0 = (const float*)d_in[1];
    const float* w_hh0 = (const float*)d_in[2];
    const float* w_ih1 = (const float*)d_in[3];
    const float* w_hh1 = (const float*)d_in[4];
    const float* w_lin = (const float*)d_in[5];
    const float* b_lin = (const float*)d_in[6];
    float* out = (float*)d_out;
    _Float16* wsp = (_Float16*)d_ws;

    const int nbatch = in_sizes[0] / 64;

    prep_kernel<<<384, 256, 0, stream>>>(w_hh0, w_ih1, w_hh1, wsp);

    const int blocks = (nbatch + 63) / 64;
    rnn_wf_pipe<<<blocks, 1024, 0, stream>>>(x, w_ih0, w_lin, b_lin, wsp, out, nbatch);
}